// Round 2
// baseline (2113.050 us; speedup 1.0000x reference)
//
#include <hip/hip_runtime.h>
#include <math.h>

// Problem constants (from reference)
#define NPTS   16384
#define KNN_K  40
#define KNN_CAP 640   // filtered-candidate buffer per row; E[count]~350, +5.4 sigma safe

// ---- bf16 (stored as ushort bits) helpers: fp32 compute, bf16 storage -----
static __device__ __forceinline__ float bf2f(unsigned short h) {
  return __uint_as_float(((unsigned)h) << 16);
}
static __device__ __forceinline__ unsigned short f2bf(float f) {
  unsigned u = __float_as_uint(f);
  unsigned r = (u + 0x7fffu + ((u >> 16) & 1u)) >> 16;   // round-nearest-even
  return (unsigned short)r;
}
static __device__ __forceinline__ float ldf(const float* p) { return *p; }
static __device__ __forceinline__ float ldf(const unsigned short* p) { return bf2f(*p); }

static __device__ __forceinline__ int wred_add(int v) {
  #pragma unroll
  for (int o = 32; o >= 1; o >>= 1) v += __shfl_xor(v, o, 64);
  return v;
}

// ---------------------------------------------------------------------------
// Generic fused GEMM: C[N x MCOLS] = (relu?)(concat(A1[:, :K1], A2[:, K1:K]) @ W + bias)
// A1/A2 are fp32 or bf16(ushort); W/bias fp32; C fp32 or bf16. fp32 accumulate.
// 64-row tile per block, 256 threads. A-tile padded (33) to kill bank conflicts.
// ---------------------------------------------------------------------------
template<int MCOLS, bool RELU, typename TIN, typename TOUT>
__global__ __launch_bounds__(256, 4) void gemm_k(
    const TIN* __restrict__ A1, int lda1,
    const TIN* __restrict__ A2, int lda2, int K1,
    const float* __restrict__ W, const float* __restrict__ bias,
    TOUT* __restrict__ C, int ldc, int K)
{
  constexpr int TCS = MCOLS / 8;          // threads across columns
  constexpr int RPT = (64 * TCS) / 256;   // rows per thread (128->4, 64->2)
  __shared__ float As[64][33];
  __shared__ float Ws[32][MCOLS];
  const int tid = threadIdx.x;
  const int row0 = blockIdx.x * 64;
  const int tc = tid % TCS, tr = tid / TCS;

  float acc[RPT][8];
  #pragma unroll
  for (int p = 0; p < RPT; ++p)
    #pragma unroll
    for (int q = 0; q < 8; ++q) acc[p][q] = 0.f;

  for (int k0 = 0; k0 < K; k0 += 32) {
    __syncthreads();
    // stage A tile 64 x 32 (zero-padded past K; two-source concat along K)
    for (int l = tid; l < 64 * 32; l += 256) {
      int r = l >> 5, c = l & 31, k = k0 + c;
      float v = 0.f;
      if (k < K) v = (k < K1) ? ldf(&A1[(size_t)(row0 + r) * lda1 + k])
                              : ldf(&A2[(size_t)(row0 + r) * lda2 + (k - K1)]);
      As[r][c] = v;
    }
    // stage W tile 32 x MCOLS
    for (int l = tid; l < 32 * MCOLS; l += 256) {
      int kr = l / MCOLS, c = l % MCOLS, k = k0 + kr;
      Ws[kr][c] = (k < K) ? W[(size_t)k * MCOLS + c] : 0.f;
    }
    __syncthreads();
    #pragma unroll
    for (int kk = 0; kk < 32; ++kk) {
      float a[RPT];
      #pragma unroll
      for (int p = 0; p < RPT; ++p) a[p] = As[tr * RPT + p][kk];
      const float4 w0 = *(const float4*)&Ws[kk][tc * 8];
      const float4 w1 = *(const float4*)&Ws[kk][tc * 8 + 4];
      #pragma unroll
      for (int p = 0; p < RPT; ++p) {
        acc[p][0] = fmaf(a[p], w0.x, acc[p][0]);
        acc[p][1] = fmaf(a[p], w0.y, acc[p][1]);
        acc[p][2] = fmaf(a[p], w0.z, acc[p][2]);
        acc[p][3] = fmaf(a[p], w0.w, acc[p][3]);
        acc[p][4] = fmaf(a[p], w1.x, acc[p][4]);
        acc[p][5] = fmaf(a[p], w1.y, acc[p][5]);
        acc[p][6] = fmaf(a[p], w1.z, acc[p][6]);
        acc[p][7] = fmaf(a[p], w1.w, acc[p][7]);
      }
    }
  }

  const float4 b0 = *(const float4*)&bias[tc * 8];
  const float4 b1 = *(const float4*)&bias[tc * 8 + 4];
  #pragma unroll
  for (int p = 0; p < RPT; ++p) {
    int r = row0 + tr * RPT + p;
    float o[8];
    o[0] = acc[p][0] + b0.x; o[1] = acc[p][1] + b0.y;
    o[2] = acc[p][2] + b0.z; o[3] = acc[p][3] + b0.w;
    o[4] = acc[p][4] + b1.x; o[5] = acc[p][5] + b1.y;
    o[6] = acc[p][6] + b1.z; o[7] = acc[p][7] + b1.w;
    if (RELU) {
      #pragma unroll
      for (int q = 0; q < 8; ++q) o[q] = fmaxf(o[q], 0.f);
    }
    if constexpr (sizeof(TOUT) == 2) {
      // pack 8 bf16 into one 16B store
      unsigned p0 = (unsigned)f2bf(o[0]) | ((unsigned)f2bf(o[1]) << 16);
      unsigned p1 = (unsigned)f2bf(o[2]) | ((unsigned)f2bf(o[3]) << 16);
      unsigned p2 = (unsigned)f2bf(o[4]) | ((unsigned)f2bf(o[5]) << 16);
      unsigned p3 = (unsigned)f2bf(o[6]) | ((unsigned)f2bf(o[7]) << 16);
      uint4 pk = make_uint4(p0, p1, p2, p3);
      *(uint4*)&C[(size_t)r * ldc + tc * 8] = pk;
    } else {
      float4 o0, o1;
      o0.x = o[0]; o0.y = o[1]; o0.z = o[2]; o0.w = o[3];
      o1.x = o[4]; o1.y = o[5]; o1.z = o[6]; o1.w = o[7];
      *(float4*)&C[(size_t)r * ldc + tc * 8] = o0;
      *(float4*)&C[(size_t)r * ldc + tc * 8 + 4] = o1;
    }
  }
}

// ---------------------------------------------------------------------------
// Small-M GEMM (M = 4): lin_s and fc4. One thread per (row, col). K <= 128.
// ---------------------------------------------------------------------------
template<bool RELU, typename TIN, typename TOUT>
__global__ __launch_bounds__(256, 2) void gemm4_k(
    const TIN* __restrict__ A, int lda,
    const float* __restrict__ W, const float* __restrict__ bias,
    TOUT* __restrict__ C, int ldc, int K)
{
  __shared__ float WsT[4][128];
  const int tid = threadIdx.x;
  for (int l = tid; l < 512; l += 256) {
    int c = l >> 7, k = l & 127;
    WsT[c][k] = (k < K) ? W[k * 4 + c] : 0.f;
  }
  __syncthreads();
  const int row = blockIdx.x * 64 + (tid >> 2);
  const int c = tid & 3;
  const TIN* ap = A + (size_t)row * lda;
  float acc = 0.f;
  for (int k = 0; k < K; ++k) acc = fmaf(ldf(&ap[k]), WsT[c][k], acc);
  float v = acc + bias[c];
  if (RELU) v = fmaxf(v, 0.f);
  if constexpr (sizeof(TOUT) == 2) C[(size_t)row * ldc + c] = (TOUT)f2bf(v);
  else                             C[(size_t)row * ldc + c] = v;
}

// ---------------------------------------------------------------------------
// Exact kNN (K=40) in 4-d s-space (fp32). One wave per row, 8 rows/512-thr blk.
// s staged in LDS chunks (1024 pts) shared by the block's 8 rows.
// Seed (first 2048 candidates in regs) -> bit-bisection threshold t0 with
// seed-count in [40,~44] (so t0 >= true 40th dist) -> filtered ballot append
// -> final bisect to <=104 -> shuffle bitonic-128 sort of (d2bits<<32|idx)
// -> exact top-40 (tie-break by index, matching lax.top_k).
// Outputs: u16 indices, bf16 weights exp(-10*d2).
// ---------------------------------------------------------------------------
__global__ __launch_bounds__(512, 4) void knn_k(
    const float* __restrict__ s,
    unsigned short* __restrict__ idx_out, unsigned short* __restrict__ w_out)
{
  __shared__ float4 spts[1024];
  __shared__ float  s2s[1024];
  __shared__ unsigned long long buf[8][KNN_CAP];

  const int tid = threadIdx.x;
  const int lane = tid & 63;
  const int w = tid >> 6;
  const int row = blockIdx.x * 8 + w;
  const float4* s4 = (const float4*)s;

  const float4 si = s4[row];
  const float s2i = fmaf(si.x, si.x, fmaf(si.y, si.y, fmaf(si.z, si.z, si.w * si.w)));

  unsigned int db[32];

  // ---- chunks 0 and 1: stage + scan into registers (seed = 2048 candidates)
  #pragma unroll
  for (int cc = 0; cc < 2; ++cc) {
    __syncthreads();
    for (int t = tid; t < 1024; t += 512) {
      float4 p = s4[cc * 1024 + t];
      spts[t] = p;
      s2s[t] = fmaf(p.x, p.x, fmaf(p.y, p.y, fmaf(p.z, p.z, p.w * p.w)));
    }
    __syncthreads();
    #pragma unroll
    for (int i = 0; i < 16; ++i) {
      int jl = i * 64 + lane;
      float4 p = spts[jl];
      float dot = fmaf(si.x, p.x, fmaf(si.y, p.y, fmaf(si.z, p.z, si.w * p.w)));
      float d2 = fmaxf(fmaf(-2.f, dot, s2i + s2s[jl]), 0.f);
      db[cc * 16 + i] = __float_as_uint(d2);
    }
  }

  // ---- bisect t0 on the seed: smallest bits with count>=40, stop at <=44
  int lo = -1, hi = 0x7f800000, chi = 2048;
  for (int it = 0; it < 32; ++it) {
    if (chi <= 44) break;
    int mid = (lo + hi) >> 1;
    unsigned um = (unsigned)mid;
    int lc = 0;
    #pragma unroll
    for (int i = 0; i < 32; ++i) lc += (db[i] <= um) ? 1 : 0;
    lc = wred_add(lc);
    if (lc >= 40) { hi = mid; chi = lc; } else lo = mid;
  }
  const unsigned t0b = (unsigned)hi;
  const float t0f = __uint_as_float(t0b);

  // ---- append seed survivors (candidate index = i*64+lane)
  int cnt = 0;
  #pragma unroll
  for (int i = 0; i < 32; ++i) {
    bool keep = (db[i] <= t0b);
    unsigned long long mask = __ballot(keep);
    if (mask) {
      int pos = cnt + (int)__popcll(mask & ((1ull << lane) - 1ull));
      if (keep && pos < KNN_CAP)
        buf[w][pos] = (((unsigned long long)db[i]) << 32) | (unsigned)(i * 64 + lane);
      cnt = min(cnt + (int)__popcll(mask), KNN_CAP);
    }
  }

  // ---- chunks 2..15: stage + filtered append
  for (int c = 2; c < 16; ++c) {
    __syncthreads();
    for (int t = tid; t < 1024; t += 512) {
      float4 p = s4[c * 1024 + t];
      spts[t] = p;
      s2s[t] = fmaf(p.x, p.x, fmaf(p.y, p.y, fmaf(p.z, p.z, p.w * p.w)));
    }
    __syncthreads();
    #pragma unroll 4
    for (int i = 0; i < 16; ++i) {
      int jl = i * 64 + lane;
      float4 p = spts[jl];
      float dot = fmaf(si.x, p.x, fmaf(si.y, p.y, fmaf(si.z, p.z, si.w * p.w)));
      float d2 = fmaxf(fmaf(-2.f, dot, s2i + s2s[jl]), 0.f);
      bool keep = (d2 <= t0f);
      unsigned long long mask = __ballot(keep);
      if (mask) {
        int pos = cnt + (int)__popcll(mask & ((1ull << lane) - 1ull));
        if (keep && pos < KNN_CAP)
          buf[w][pos] = (((unsigned long long)__float_as_uint(d2)) << 32)
                        | (unsigned)(c * 1024 + jl);
        cnt = min(cnt + (int)__popcll(mask), KNN_CAP);
      }
    }
  }

  __syncthreads();   // all waves done reading spts; safe to reuse as scratch

  // ---- final bisect on buffer: threshold t1 with count in [40, 104]
  lo = -1; hi = (int)t0b; chi = cnt;
  for (int it = 0; it < 32; ++it) {
    if (chi <= 104) break;
    int mid = (lo + hi) >> 1;
    unsigned um = (unsigned)mid;
    int lc = 0;
    for (int i2 = lane; i2 < cnt; i2 += 64)
      lc += ((unsigned)(buf[w][i2] >> 32) <= um) ? 1 : 0;
    lc = wred_add(lc);
    if (lc >= 40) { hi = mid; chi = lc; } else lo = mid;
  }
  const unsigned t1b = (unsigned)hi;

  // ---- compact survivors into per-wave scratch (1 KiB of spts per wave)
  unsigned long long* scratch = (unsigned long long*)&spts[w * 64];
  scratch[lane * 2] = ~0ull;
  scratch[lane * 2 + 1] = ~0ull;
  int taken = 0;
  int steps = (cnt + 63) >> 6;
  for (int i = 0; i < steps; ++i) {
    int sidx = i * 64 + lane;
    unsigned long long key = (sidx < cnt) ? buf[w][sidx] : ~0ull;
    bool keep = (sidx < cnt) && ((unsigned)(key >> 32) <= t1b);
    unsigned long long mask = __ballot(keep);
    int pos = taken + (int)__popcll(mask & ((1ull << lane) - 1ull));
    if (keep && pos < 128) scratch[pos] = key;
    taken = min(taken + (int)__popcll(mask), 128);
  }

  // ---- bitonic sort of 128 keys, 2 per lane, ascending (d2, then idx)
  unsigned long long e0 = scratch[lane * 2], e1 = scratch[lane * 2 + 1];
  #pragma unroll
  for (int k = 2; k <= 128; k <<= 1) {
    #pragma unroll
    for (int j = k >> 1; j >= 1; j >>= 1) {
      bool up = (((lane * 2) & k) == 0);
      if (j == 1) {
        unsigned long long a = (e0 < e1) ? e0 : e1;
        unsigned long long b = (e0 < e1) ? e1 : e0;
        e0 = up ? a : b; e1 = up ? b : a;
      } else {
        int lj = j >> 1;
        bool lower = ((lane & lj) == 0);
        bool tm = (up == lower);
        unsigned long long o0 = __shfl_xor(e0, lj, 64);
        e0 = tm ? ((e0 < o0) ? e0 : o0) : ((e0 > o0) ? e0 : o0);
        unsigned long long o1 = __shfl_xor(e1, lj, 64);
        e1 = tm ? ((e1 < o1) ? e1 : o1) : ((e1 > o1) ? e1 : o1);
      }
    }
  }

  // ---- emit top-40: u16 idx and bf16 weight exp(-10*d2)
  const int ob = row * KNN_K;
  if (lane < 20) {
    int v0 = lane * 2;
    idx_out[ob + v0] = (unsigned short)(e0 & 0xffffu);
    w_out[ob + v0] = f2bf(__expf(-10.f * __uint_as_float((unsigned)(e0 >> 32))));
    int v1 = v0 + 1;
    idx_out[ob + v1] = (unsigned short)(e1 & 0xffffu);
    w_out[ob + v1] = f2bf(__expf(-10.f * __uint_as_float((unsigned)(e1 >> 32))));
  }
}

// ---------------------------------------------------------------------------
// Aggregation: Aout[i] = [mean_k h[idx]*w | max_k h[idx]*w]  (N x 128, bf16).
// One wave per row (lane = channel of 64), 4 rows per block.
// ---------------------------------------------------------------------------
__global__ __launch_bounds__(256, 4) void agg_k(
    const unsigned short* __restrict__ h, const unsigned short* __restrict__ idxb,
    const unsigned short* __restrict__ wb, unsigned short* __restrict__ Aout)
{
  const int row = blockIdx.x * 4 + (threadIdx.x >> 6);
  const int lane = threadIdx.x & 63;
  const int base = row * KNN_K;
  float mean = 0.f, mx = -INFINITY;
  #pragma unroll 4
  for (int k = 0; k < KNN_K; ++k) {
    int j = idxb[base + k];
    float wv = bf2f(wb[base + k]);
    float m = bf2f(h[(size_t)j * 64 + lane]) * wv;
    mean += m;
    mx = fmaxf(mx, m);
  }
  Aout[(size_t)row * 128 + lane] = f2bf(mean * (1.f / 40.f));
  Aout[(size_t)row * 128 + 64 + lane] = f2bf(mx);
}

// ---------------------------------------------------------------------------
extern "C" void kernel_launch(void* const* d_in, const int* in_sizes, int n_in,
                              void* d_out, int out_size, void* d_ws, size_t ws_size,
                              hipStream_t stream)
{
  const float* x    = (const float*)d_in[0];
  const float* fc1W = (const float*)d_in[1];  const float* fc1b = (const float*)d_in[2];
  const float* fc2W = (const float*)d_in[3];  const float* fc2b = (const float*)d_in[4];
  const float* gsW  = (const float*)d_in[5];  const float* gsb  = (const float*)d_in[6];
  const float* ghW  = (const float*)d_in[7];  const float* ghb  = (const float*)d_in[8];
  const float* goW  = (const float*)d_in[9];  const float* gob  = (const float*)d_in[10];
  const float* d1W  = (const float*)d_in[11]; const float* d1b  = (const float*)d_in[12];
  const float* d2W  = (const float*)d_in[13]; const float* d2b  = (const float*)d_in[14];
  const float* d3W  = (const float*)d_in[15]; const float* d3b  = (const float*)d_in[16];
  const float* fc3W = (const float*)d_in[17]; const float* fc3b = (const float*)d_in[18];
  const float* fc4W = (const float*)d_in[19]; const float* fc4b = (const float*)d_in[20];
  float* out = (float*)d_out;

  // ---- workspace layout: 14.5 MiB total (bf16 activations, u16 idx) ----
  // X    : N*128 bf16  (current features)
  // Abuf : N*128 bf16  (agg output; fp32 S[N,4] aliased at its start pre-agg)
  // T    : N*128 bf16  (temp; bf16 H[N,64] aliased at its start pre-lin_out)
  // IDX  : N*40  u16
  // WNB  : N*40  bf16
  const size_t N = NPTS;
  unsigned short* X    = (unsigned short*)d_ws;
  unsigned short* Abuf = X + N * 128;
  unsigned short* T    = Abuf + N * 128;
  unsigned short* IDX  = T + N * 128;
  unsigned short* WNB  = IDX + N * 40;
  float* S = (float*)Abuf;        // N*4 fp32 == N*8 ushorts, inside Abuf
  unsigned short* H = T;          // N*64 bf16, inside T

  typedef unsigned short u16;

  // fc1 (K=9, fp32 input) + relu -> T ; fc2 + relu -> X
  gemm_k<128, true, float, u16><<<NPTS / 64, 256, 0, stream>>>(
      x, 9, x, 9, 9, fc1W, fc1b, T, 128, 9);
  gemm_k<128, true, u16, u16><<<NPTS / 64, 256, 0, stream>>>(
      T, 128, T, 128, 128, fc2W, fc2b, X, 128, 128);

  for (int l = 0; l < 4; ++l) {
    // lin_s -> S (fp32, in Abuf); lin_h -> H (bf16, in T)
    gemm4_k<false, u16, float><<<NPTS / 64, 256, 0, stream>>>(
        X, 128, gsW + l * 128 * 4, gsb + l * 4, S, 4, 128);
    gemm_k<64, false, u16, u16><<<NPTS / 64, 256, 0, stream>>>(
        X, 128, X, 128, 128, ghW + l * 128 * 64, ghb + l * 64, H, 64, 128);
    // exact kNN(40) + weights
    knn_k<<<NPTS / 8, 512, 0, stream>>>(S, IDX, WNB);
    // aggregation -> Abuf (overwrites S, which is dead now)
    agg_k<<<NPTS / 4, 256, 0, stream>>>(H, IDX, WNB, Abuf);
    // lin_out: concat(X, Abuf) K=256 -> T (no relu; overwrites H, dead now)
    gemm_k<128, false, u16, u16><<<NPTS / 64, 256, 0, stream>>>(
        X, 128, Abuf, 128, 128, goW + l * 256 * 128, gob + l * 128, T, 128, 256);
    // dense_after_gravnet: d1 -> Abuf, d2 -> T, d3 -> X
    gemm_k<128, true, u16, u16><<<NPTS / 64, 256, 0, stream>>>(
        T, 128, T, 128, 128, d1W + l * 128 * 128, d1b + l * 128, Abuf, 128, 128);
    gemm_k<128, true, u16, u16><<<NPTS / 64, 256, 0, stream>>>(
        Abuf, 128, Abuf, 128, 128, d2W + l * 128 * 128, d2b + l * 128, T, 128, 128);
    gemm_k<128, true, u16, u16><<<NPTS / 64, 256, 0, stream>>>(
        T, 128, T, 128, 128, d3W + l * 128 * 128, d3b + l * 128, X, 128, 128);
  }

  // fc3 + relu -> T ; fc4 -> out (fp32, N x 4)
  gemm_k<128, true, u16, u16><<<NPTS / 64, 256, 0, stream>>>(
      X, 128, X, 128, 128, fc3W, fc3b, T, 128, 128);
  gemm4_k<false, u16, float><<<NPTS / 64, 256, 0, stream>>>(
      T, 128, fc4W, fc4b, out, 4, 128);
}